// Round 1
// baseline (99183.417 us; speedup 1.0000x reference)
//
#include <hip/hip_runtime.h>
#include <hip/hip_cooperative_groups.h>

namespace cg = cooperative_groups;

constexpr int   NROWS   = 65536;
constexpr int   NK      = 1024;
constexpr float PAv     = 1.0f / 65536.0f;
constexpr float PBv     = 1.0f / 1024.0f;
constexpr float FI      = 1.0f / 1.1f;        // GAMMA/(GAMMA+eps)
constexpr float NEG_INV_EPS = -10.0f;         // -1/eps
constexpr float STOPERR2 = 1e-12f;            // (1e-6)^2, compare sum of squares
constexpr int   MAXIT   = 1000;

// ---------------- cooperative Sinkhorn iteration kernel ----------------
constexpr int IT_BLOCKS  = 256;
constexpr int IT_THREADS = 1024;
constexpr int IT_WAVES   = IT_THREADS / 64;                 // 16
constexpr int IT_RPW     = NROWS / (IT_BLOCKS * IT_WAVES);  // 16 rows per wave

__global__ __launch_bounds__(IT_THREADS, 4)
void ssk_iter_kernel(const float* __restrict__ P, float* __restrict__ cs0,
                     float* __restrict__ cs1, float* __restrict__ b_out)
{
  cg::grid_group grid = cg::this_grid();
  __shared__ float b_lds[NK];
  __shared__ float wave_cs[IT_WAVES][NK];   // 64 KiB
  __shared__ float red[IT_WAVES];
  __shared__ float err_sh;

  const int tid  = threadIdx.x;
  const int wave = tid >> 6;
  const int lane = tid & 63;
  const int row0 = blockIdx.x * (IT_WAVES * IT_RPW) + wave * IT_RPW;

  b_lds[tid] = PBv;                         // b0 = 1/K
  __syncthreads();

  int it = 0;
  for (;;) {
    float* __restrict__ cs_cur  = (it & 1) ? cs1 : cs0;   // accum target this iter
    float* __restrict__ cs_next = (it & 1) ? cs0 : cs1;   // zero for next iter
    cs_next[tid] = 0.0f;

    // lane-private b values for its 16 columns: col = 256*k + 4*lane + j
    float bb[16], acc[16];
    #pragma unroll
    for (int k = 0; k < 4; ++k)
      #pragma unroll
      for (int j = 0; j < 4; ++j)
        bb[4*k + j] = b_lds[256*k + 4*lane + j];
    #pragma unroll
    for (int t = 0; t < 16; ++t) acc[t] = 0.0f;

    for (int r = 0; r < IT_RPW; ++r) {
      const float4* rp = reinterpret_cast<const float4*>(P) + (size_t)(row0 + r) * (NK / 4);
      float Q[16];
      float dot = 0.0f;
      #pragma unroll
      for (int k = 0; k < 4; ++k) {
        float4 v = rp[(k << 6) + lane];
        Q[4*k+0] = __expf(v.x * NEG_INV_EPS);
        Q[4*k+1] = __expf(v.y * NEG_INV_EPS);
        Q[4*k+2] = __expf(v.z * NEG_INV_EPS);
        Q[4*k+3] = __expf(v.w * NEG_INV_EPS);
        dot = fmaf(Q[4*k+0], bb[4*k+0], dot);
        dot = fmaf(Q[4*k+1], bb[4*k+1], dot);
        dot = fmaf(Q[4*k+2], bb[4*k+2], dot);
        dot = fmaf(Q[4*k+3], bb[4*k+3], dot);
      }
      #pragma unroll
      for (int off = 32; off > 0; off >>= 1) dot += __shfl_xor(dot, off);
      float a = PAv / fmaxf(dot, 1e-12f);   // a_i = Pa / max(Q b, 1e-12)
      #pragma unroll
      for (int t = 0; t < 16; ++t) acc[t] = fmaf(a, Q[t], acc[t]);  // Q^T a partial
    }

    // block-level column reduction, then one atomic per column per block
    #pragma unroll
    for (int k = 0; k < 4; ++k)
      #pragma unroll
      for (int j = 0; j < 4; ++j)
        wave_cs[wave][256*k + 4*lane + j] = acc[4*k + j];
    __syncthreads();
    {
      float s = 0.0f;
      #pragma unroll
      for (int w = 0; w < IT_WAVES; ++w) s += wave_cs[w][tid];
      atomicAdd(&cs_cur[tid], s);
    }

    grid.sync();

    // Phase B: every block redundantly (bit-identically) computes b_new + err
    float cs = cs_cur[tid];
    float bn = powf(PBv / fmaxf(cs, 1e-12f), FI);
    float d  = bn - b_lds[tid];
    float sq = d * d;
    #pragma unroll
    for (int off = 32; off > 0; off >>= 1) sq += __shfl_xor(sq, off);
    if (lane == 0) red[wave] = sq;
    __syncthreads();
    if (tid == 0) {
      float e = 0.0f;
      #pragma unroll
      for (int w = 0; w < IT_WAVES; ++w) e += red[w];
      err_sh = e;
    }
    b_lds[tid] = bn;
    ++it;
    __syncthreads();
    const bool done = (err_sh <= STOPERR2) || (it >= MAXIT);
    grid.sync();               // protects cs_cur reads vs next-iter zeroing
    if (done) break;
  }

  if (blockIdx.x == 0) b_out[tid] = b_lds[tid];
}

// ---------------- finalize: OT_plan + partial reductions ----------------
constexpr int FN_BLOCKS  = 2048;
constexpr int FN_THREADS = 256;
constexpr int FN_WAVES   = FN_THREADS / 64;                  // 4
constexpr int FN_RPW     = NROWS / (FN_BLOCKS * FN_WAVES);   // 8

__global__ __launch_bounds__(FN_THREADS)
void ssk_finalize_kernel(const float* __restrict__ P, const float* __restrict__ b_glob,
                         float* __restrict__ out, float* __restrict__ wsum,
                         float* __restrict__ loss_part)
{
  __shared__ float b_sh[NK];
  __shared__ float wave_w[FN_WAVES][NK];   // 16 KiB
  __shared__ float red[FN_WAVES];

  const int tid  = threadIdx.x;
  const int wave = tid >> 6;
  const int lane = tid & 63;

  #pragma unroll
  for (int i = 0; i < 4; ++i) b_sh[tid + 256*i] = b_glob[tid + 256*i];
  __syncthreads();

  float bb[16];
  #pragma unroll
  for (int k = 0; k < 4; ++k)
    #pragma unroll
    for (int j = 0; j < 4; ++j)
      bb[4*k + j] = b_sh[256*k + 4*lane + j];

  float wacc[16];
  #pragma unroll
  for (int t = 0; t < 16; ++t) wacc[t] = 0.0f;
  float lacc = 0.0f;

  const int row0 = (blockIdx.x * FN_WAVES + wave) * FN_RPW;
  float4* out4 = reinterpret_cast<float4*>(out);

  for (int r = 0; r < FN_RPW; ++r) {
    const size_t row = (size_t)(row0 + r);
    const float4* rp = reinterpret_cast<const float4*>(P) + row * (NK / 4);
    float4 pv[4];
    float Q[16];
    float dot = 0.0f;
    #pragma unroll
    for (int k = 0; k < 4; ++k) {
      pv[k] = rp[(k << 6) + lane];
      Q[4*k+0] = __expf(pv[k].x * NEG_INV_EPS);
      Q[4*k+1] = __expf(pv[k].y * NEG_INV_EPS);
      Q[4*k+2] = __expf(pv[k].z * NEG_INV_EPS);
      Q[4*k+3] = __expf(pv[k].w * NEG_INV_EPS);
      dot = fmaf(Q[4*k+0], bb[4*k+0], dot);
      dot = fmaf(Q[4*k+1], bb[4*k+1], dot);
      dot = fmaf(Q[4*k+2], bb[4*k+2], dot);
      dot = fmaf(Q[4*k+3], bb[4*k+3], dot);
    }
    #pragma unroll
    for (int off = 32; off > 0; off >>= 1) dot += __shfl_xor(dot, off);
    const float s = 1.0f / fmaxf(dot, 1e-12f);    // N * a_i  (N*Pa = 1)
    #pragma unroll
    for (int k = 0; k < 4; ++k) {
      float4 o;
      o.x = s * Q[4*k+0] * bb[4*k+0];
      o.y = s * Q[4*k+1] * bb[4*k+1];
      o.z = s * Q[4*k+2] * bb[4*k+2];
      o.w = s * Q[4*k+3] * bb[4*k+3];
      out4[row * (NK / 4) + (k << 6) + lane] = o;
      lacc = fmaf(o.x, pv[k].x, lacc);
      lacc = fmaf(o.y, pv[k].y, lacc);
      lacc = fmaf(o.z, pv[k].z, lacc);
      lacc = fmaf(o.w, pv[k].w, lacc);
      wacc[4*k+0] += o.x; wacc[4*k+1] += o.y; wacc[4*k+2] += o.z; wacc[4*k+3] += o.w;
    }
  }

  // column partial sums for w
  #pragma unroll
  for (int k = 0; k < 4; ++k)
    #pragma unroll
    for (int j = 0; j < 4; ++j)
      wave_w[wave][256*k + 4*lane + j] = wacc[4*k + j];
  __syncthreads();
  #pragma unroll
  for (int i = 0; i < 4; ++i) {
    const int c = tid + 256*i;
    float s2 = wave_w[0][c] + wave_w[1][c] + wave_w[2][c] + wave_w[3][c];
    atomicAdd(&wsum[c], s2);
  }

  // loss partial per block
  #pragma unroll
  for (int off = 32; off > 0; off >>= 1) lacc += __shfl_xor(lacc, off);
  if (lane == 0) red[wave] = lacc;
  __syncthreads();
  if (tid == 0) loss_part[blockIdx.x] = red[0] + red[1] + red[2] + red[3];
}

// ---------------- finish: scalars ----------------
__device__ __forceinline__ float ssk_block_sum_1024(float v, float* red, int wave, int lane)
{
  #pragma unroll
  for (int off = 32; off > 0; off >>= 1) v += __shfl_xor(v, off);
  __syncthreads();
  if (lane == 0) red[wave] = v;
  __syncthreads();
  float t = 0.0f;
  #pragma unroll
  for (int w = 0; w < 16; ++w) t += red[w];
  return t;
}

__global__ __launch_bounds__(1024)
void ssk_finish_kernel(const float* __restrict__ wsum, const float* __restrict__ loss_part,
                       float* __restrict__ out)
{
  __shared__ float red[16];
  const int tid = threadIdx.x, wave = tid >> 6, lane = tid & 63;

  float l  = loss_part[tid] + loss_part[tid + 1024];
  float lt = ssk_block_sum_1024(l, red, wave, lane);

  float wm = wsum[tid] * (1.0f / (float)NROWS);   // w = colmean(OT)
  float sw = ssk_block_sum_1024(wm, red, wave, lane);
  float wn = wm / (sw + 1e-8f);
  float v  = PBv * (logf(PBv) - logf(wn + 1e-7f));
  float rg = ssk_block_sum_1024(v, red, wave, lane);

  if (tid == 0) {
    out[(size_t)NROWS * NK]     = lt / (float)NROWS;  // ot_loss
    out[(size_t)NROWS * NK + 1] = rg;                 // reg
  }
}

// ---------------- launch ----------------
extern "C" void kernel_launch(void* const* d_in, const int* in_sizes, int n_in,
                              void* d_out, int out_size, void* d_ws, size_t ws_size,
                              hipStream_t stream)
{
  const float* P = (const float*)d_in[0];
  float* out = (float*)d_out;
  float* ws  = (float*)d_ws;

  float* cs0       = ws;             // [1024]
  float* cs1       = ws + 1024;      // [1024]
  float* b_glob    = ws + 2048;      // [1024]
  float* wsum      = ws + 3072;      // [1024]
  float* loss_part = ws + 4096;      // [2048]

  // zero cs0 (iter-0 accum target), cs1, b_glob, wsum
  hipMemsetAsync(ws, 0, 4096 * sizeof(float), stream);

  void* args[] = { (void*)&P, (void*)&cs0, (void*)&cs1, (void*)&b_glob };
  hipLaunchCooperativeKernel((void*)ssk_iter_kernel, dim3(IT_BLOCKS), dim3(IT_THREADS),
                             args, 0, stream);

  ssk_finalize_kernel<<<dim3(FN_BLOCKS), dim3(FN_THREADS), 0, stream>>>(
      P, b_glob, out, wsum, loss_part);
  ssk_finish_kernel<<<dim3(1), dim3(1024), 0, stream>>>(wsum, loss_part, out);
}